// Round 9
// baseline (198.722 us; speedup 1.0000x reference)
//
#include <hip/hip_runtime.h>
#include <math.h>

#define N_PTS 8192
#define QPW 4                 // queries per wave (top-K roles)
#define QPW_REV 8             // queries per wave (reverse chamfer role)
#define WPB 4                 // waves per block
#define QPB (QPW * WPB)       // 16 queries per block (top-K roles)
#define BLKS_TOPK (N_PTS / QPB)        // 512 blocks per top-K role
#define BLKS_REV  (N_PTS / (QPW_REV * WPB))  // 256 blocks for rev

#define R0_END BLKS_TOPK                  // 512   curv2 scan
#define R1_END (2 * BLKS_TOPK)            // 1024  pc1 scan
#define R3_END (3 * BLKS_TOPK)            // 1536  cross scan
#define GRID_TOTAL (3 * BLKS_TOPK + BLKS_REV)  // 1792

// windowed scan sizes (sorted-x candidate windows)
#define WTOP 2048
#define NIT_TOP (WTOP / 256)   // 8 iters of 4-strip
#define WREV 1024
#define NIT_REV (WREV / 128)   // 8 iters of 2-strip

// bin-level counting sort
#define NBINS 2048
#define XMIN (-10.0f)
#define BINWF (20.0f / (float)NBINS)

// F_CHAMFER*ALPHA0 = 0.02, F_CURVATURE*ALPHA0 = 0.006, F_SMOOTH*ALPHA0 = 0.01
#define W_CHAM 0.02f
#define W_CURV 0.006f
#define W_SMOO 0.01f

#define BIGF 1e30f
#define IDX_MASK 0x1FFFu
#define KEY_MASK 0xFFFFE000u

__device__ __forceinline__ float mkkey(float d, unsigned idx) {
    return __uint_as_float((__float_as_uint(d) & KEY_MASK) | idx);
}
__device__ __forceinline__ int keyidx(float k) {
    return (int)(__float_as_uint(k) & IDX_MASK);
}
__device__ __forceinline__ unsigned monou(float k) {
    int b = __float_as_int(k);
    return (unsigned)(b ^ ((b >> 31) | 0x80000000));
}
__device__ __forceinline__ int prefcnt(unsigned long long m) {
    return __builtin_amdgcn_mbcnt_hi((unsigned)(m >> 32),
           __builtin_amdgcn_mbcnt_lo((unsigned)m, 0));
}

// ---- value-only sorted insert (fallback path only; proven) ----
template <int K>
__device__ __forceinline__ void kinsert(float kv, float (&bd)[K]) {
    bd[K - 1] = kv;
#pragma unroll
    for (int s = K - 1; s > 0; --s) {
        float lo = fminf(bd[s - 1], bd[s]);
        float hi = fmaxf(bd[s - 1], bd[s]);
        bd[s - 1] = lo; bd[s] = hi;
    }
}

// ---- proven sorted merge (cold failsafe only) ----
template <int K>
__device__ void merge_keys(float m1, float m2, float m3, float (&bd)[K], int lane) {
    float h0 = m1, h1 = m2, h2 = m3;
#pragma unroll
    for (int r = 0; r < K; ++r) {
        float bv = h0;
#pragma unroll
        for (int off = 1; off < 64; off <<= 1) bv = fminf(bv, __shfl_xor(bv, off));
        bd[r] = bv;
        if (h0 == bv) { h0 = h1; h1 = h2; h2 = BIGF; }
    }
}

// ---- exact fixed-tau FULL rescan over ORIGINAL array (proven exact) ----
template <int K>
__device__ void tau_rescan(const float4* __restrict__ cand,
                           float nqx, float nqy, float nqz, float tau,
                           float (&bd)[K], int lane) {
#pragma unroll
    for (int r = 0; r < K; ++r) bd[r] = BIGF;
    const float4* cp = cand + lane;
    unsigned ib = (unsigned)lane;
    for (int it = 0; it < N_PTS / 64; ++it) {
        float4 p = cp[it * 64];
        float d = fmaf(p.x, nqx, fmaf(p.y, nqy, fmaf(p.z, nqz, p.w)));
        float kc = mkkey(d, ib);
        unsigned long long m = __ballot(kc <= tau);
        while (m) {
            int b = __builtin_ctzll(m);
            m &= m - 1;
            float kv = __shfl(kc, b);
            if (kv < bd[K - 1]) kinsert<K>(kv, bd);
        }
        ib += 64;
    }
}

// ---- rank-pivot set selection over windowed keys + window certificate ----
// certG (shifted space): if !(certG > km) the window may miss a true member
// -> exact full tau_rescan over the ORIGINAL array (cand). km >= global Kth
// key always (window Kth >= global Kth), so tau_rescan(km) is exact.
template <int K>
__device__ void select_set(const float4* __restrict__ cand,
                           float nqx, float nqy, float nqz, float certG,
                           float& k1, float& k2, float& k3,
                           bool& q1, bool& q2, bool& q3, float& km, int lane) {
    const unsigned u1 = monou(k1), u2 = monou(k2), u3 = monou(k3);
    float bmn = k1, bmx = k1;
#pragma unroll
    for (int off = 1; off < 64; off <<= 1) {
        bmn = fminf(bmn, __shfl_xor(bmn, off));
        bmx = fmaxf(bmx, __shfl_xor(bmx, off));
    }
    unsigned lo = monou(bmn), hi = monou(bmx), piv = 0u;
    int cnt = -1;
    unsigned long long b3 = 0ull;
    for (int it = 0; it < 34; ++it) {
        piv = lo + ((hi - lo) >> 1);
        unsigned long long b1 = __ballot(u1 <= piv);
        unsigned long long b2 = __ballot(u2 <= piv);
        b3 = __ballot(u3 <= piv);
        cnt = __popcll(b1) + __popcll(b2) + __popcll(b3);
        if (cnt == K) break;
        if (cnt < K) lo = piv + 1; else hi = piv - 1;
    }
    bool setok = (cnt == K);
    bool fail;
    float bdK[K];
    if (setok) {
        q1 = (u1 <= piv); q2 = (u2 <= piv); q3 = (u3 <= piv);
        float t = q3 ? k3 : (q2 ? k2 : (q1 ? k1 : -BIGF));
#pragma unroll
        for (int off = 1; off < 64; off <<= 1) t = fmaxf(t, __shfl_xor(t, off));
        km = t;
        fail = (b3 != 0ull) || !(certG > km);
    } else {
        merge_keys<K>(k1, k2, k3, bdK, lane);
        km = bdK[K - 1];
        fail = (__ballot(k3 <= km) != 0ull) || !(certG > km);
    }
    if (fail) { tau_rescan<K>(cand, nqx, nqy, nqz, km, bdK, lane); setok = false; }
    if (!setok) {
        float kv = BIGF;
#pragma unroll
        for (int r = 0; r < K; ++r) if (lane == r) kv = bdK[r];
        k1 = kv; k2 = BIGF; k3 = BIGF;
        q1 = (lane < K); q2 = false; q3 = false;
        km = bdK[K - 1];
    }
}

__device__ __forceinline__ void wave_add3(float& a, float& b, float& c) {
#pragma unroll
    for (int off = 1; off < 64; off <<= 1) {
        a += __shfl_xor(a, off);
        b += __shfl_xor(b, off);
        c += __shfl_xor(c, off);
    }
}
__device__ __forceinline__ void wave_add4(float& a, float& b, float& c, float& d) {
#pragma unroll
    for (int off = 1; off < 64; off <<= 1) {
        a += __shfl_xor(a, off);
        b += __shfl_xor(b, off);
        c += __shfl_xor(c, off);
        d += __shfl_xor(d, off);
    }
}

// wave-uniform binary search: last index with s[idx].x <= x (bin-level order ok;
// result only centers the window — certificates guarantee exactness)
__device__ __forceinline__ int wave_bsearch(const float4* __restrict__ s, float x) {
    int lo = 0, hi = N_PTS;
    while (hi - lo > 1) {
        int m = (lo + hi) >> 1;
        if (s[m].x <= x) lo = m; else hi = m;
    }
    return lo;
}

// ---- windowed Q-query key scan over sorted candidates (orig idx in .w bits) ----
template <int Q>
__device__ __forceinline__ void scankw(const float4* __restrict__ cw,
                                       const float (&nqx)[Q], const float (&nqy)[Q],
                                       const float (&nqz)[Q],
                                       float (&m1)[Q], float (&m2)[Q], float (&m3)[Q],
                                       int lane) {
#pragma unroll
    for (int qi = 0; qi < Q; ++qi) { m1[qi] = BIGF; m2[qi] = BIGF; m3[qi] = BIGF; }
    const float4* cp = cw + lane;
    for (int it = 0; it < NIT_TOP; ++it) {
        float4 p0 = cp[it * 256 + 0];
        float4 p1 = cp[it * 256 + 64];
        float4 p2 = cp[it * 256 + 128];
        float4 p3 = cp[it * 256 + 192];
        float s0 = fmaf(p0.z, p0.z, fmaf(p0.y, p0.y, p0.x * p0.x));
        float s1 = fmaf(p1.z, p1.z, fmaf(p1.y, p1.y, p1.x * p1.x));
        float s2 = fmaf(p2.z, p2.z, fmaf(p2.y, p2.y, p2.x * p2.x));
        float s3 = fmaf(p3.z, p3.z, fmaf(p3.y, p3.y, p3.x * p3.x));
        unsigned i0 = __float_as_uint(p0.w);
        unsigned i1 = __float_as_uint(p1.w);
        unsigned i2 = __float_as_uint(p2.w);
        unsigned i3 = __float_as_uint(p3.w);
#pragma unroll
        for (int qi = 0; qi < Q; ++qi) {
            float d0 = fmaf(p0.x, nqx[qi], fmaf(p0.y, nqy[qi], fmaf(p0.z, nqz[qi], s0)));
            float k0 = mkkey(d0, i0);
            m3[qi] = __builtin_amdgcn_fmed3f(k0, m2[qi], m3[qi]);
            m2[qi] = __builtin_amdgcn_fmed3f(k0, m1[qi], m2[qi]);
            m1[qi] = fminf(k0, m1[qi]);
            float d1 = fmaf(p1.x, nqx[qi], fmaf(p1.y, nqy[qi], fmaf(p1.z, nqz[qi], s1)));
            float k1 = mkkey(d1, i1);
            m3[qi] = __builtin_amdgcn_fmed3f(k1, m2[qi], m3[qi]);
            m2[qi] = __builtin_amdgcn_fmed3f(k1, m1[qi], m2[qi]);
            m1[qi] = fminf(k1, m1[qi]);
            float d2 = fmaf(p2.x, nqx[qi], fmaf(p2.y, nqy[qi], fmaf(p2.z, nqz[qi], s2)));
            float k2 = mkkey(d2, i2);
            m3[qi] = __builtin_amdgcn_fmed3f(k2, m2[qi], m3[qi]);
            m2[qi] = __builtin_amdgcn_fmed3f(k2, m1[qi], m2[qi]);
            m1[qi] = fminf(k2, m1[qi]);
            float d3 = fmaf(p3.x, nqx[qi], fmaf(p3.y, nqy[qi], fmaf(p3.z, nqz[qi], s3)));
            float k3 = mkkey(d3, i3);
            m3[qi] = __builtin_amdgcn_fmed3f(k3, m2[qi], m3[qi]);
            m2[qi] = __builtin_amdgcn_fmed3f(k3, m1[qi], m2[qi]);
            m1[qi] = fminf(k3, m1[qi]);
        }
    }
}

// ---- kernel 0: pack point sets as float4 (xyz,|p|^2), zero accumulators ----
__global__ void prep_kernel(const float* __restrict__ flow, const float* __restrict__ gt,
                            const float* __restrict__ coords,
                            float4* __restrict__ p1q, float4* __restrict__ p2q,
                            float4* __restrict__ wq, float* __restrict__ accs,
                            int* __restrict__ done) {
    int i = blockIdx.x * blockDim.x + threadIdx.x;
    if (i < N_PTS) {
        float cx = coords[3 * i + 0], cy = coords[3 * i + 1], cz = coords[3 * i + 2];
        float p2x = cx + gt[3 * i + 0], p2y = cy + gt[3 * i + 1], p2z = cz + gt[3 * i + 2];
        float wx = cx + flow[3 * i + 0], wy = cy + flow[3 * i + 1], wz = cz + flow[3 * i + 2];
        p1q[i] = make_float4(cx, cy, cz, cx * cx + cy * cy + cz * cz);
        p2q[i] = make_float4(p2x, p2y, p2z, p2x * p2x + p2y * p2y + p2z * p2z);
        wq[i]  = make_float4(wx, wy, wz, wx * wx + wy * wy + wz * wz);
    }
    if (i < 8) accs[i] = 0.0f;
    if (i == 8) done[0] = 0;
}

// ---- kernel 0.5: bin-level counting sort by x; .w carries orig idx bits ----
__global__ __launch_bounds__(1024) void sort_kernel(const float4* __restrict__ p1q,
                                                    const float4* __restrict__ p2q,
                                                    const float4* __restrict__ wq,
                                                    float4* __restrict__ sp1,
                                                    float4* __restrict__ sp2,
                                                    float4* __restrict__ swq) {
    const float4* src = (blockIdx.x == 0) ? p1q : (blockIdx.x == 1) ? p2q : wq;
    float4* dst = (blockIdx.x == 0) ? sp1 : (blockIdx.x == 1) ? sp2 : swq;
    __shared__ int ha[NBINS];
    __shared__ int hb[NBINS];
    const int tid = threadIdx.x;
    for (int i = tid; i < NBINS; i += 1024) ha[i] = 0;
    __syncthreads();
    int pb[N_PTS / 1024];
#pragma unroll
    for (int r = 0; r < N_PTS / 1024; ++r) {
        int i = tid + r * 1024;
        float x = src[i].x;
        int b = (int)((x - XMIN) * (1.0f / BINWF));
        b = min(max(b, 0), NBINS - 1);
        pb[r] = b;
        atomicAdd(&ha[b], 1);
    }
    __syncthreads();
    // inclusive scan, ping-pong
    int* a = ha; int* b2 = hb;
    for (int off = 1; off < NBINS; off <<= 1) {
        for (int i = tid; i < NBINS; i += 1024) {
            int v = a[i];
            if (i >= off) v += a[i - off];
            b2[i] = v;
        }
        __syncthreads();
        int* t = a; a = b2; b2 = t;
    }
    // exclusive offsets into b2 (the free buffer)
    for (int i = tid; i < NBINS; i += 1024) b2[i] = (i == 0) ? 0 : a[i - 1];
    __syncthreads();
#pragma unroll
    for (int r = 0; r < N_PTS / 1024; ++r) {
        int i = tid + r * 1024;
        int pos = atomicAdd(&b2[pb[r]], 1);
        float4 t = src[i];
        dst[pos] = make_float4(t.x, t.y, t.z, __uint_as_float((unsigned)i));
    }
}

// per-query window certificate in shifted-key space.
// gap = x-distance to outside region (bin-conservative, -BINWF);
// certG = gap^2 - |q|^2 with 0.2% relative margin (> 2^-10 key truncation).
__device__ __forceinline__ float cert_bound(bool okl, bool okr, float xl, float xr,
                                            float xq, float qs) {
    float Gl = BIGF, Gr = BIGF;
    if (!okl) { float g = xq - xl - BINWF; Gl = (g > 0.f) ? fmaf(g, g, -qs) : -BIGF; }
    if (!okr) { float g = xr - BINWF - xq; Gr = (g > 0.f) ? fmaf(g, g, -qs) : -BIGF; }
    float G = fminf(Gl, Gr);
    return G - fabsf(G) * 0.002f - 1e-12f;
}

// ---- fused kernel: windowed scans + certificate-guarded exact fallbacks ----
// Plain __launch_bounds__(256): NEVER the 2-arg form (R18/R22 spill disasters).
__global__ __launch_bounds__(256) void fused4_kernel(const float4* __restrict__ p1q,
                                                     const float4* __restrict__ p2q,
                                                     const float4* __restrict__ wq,
                                                     const float4* __restrict__ sp1,
                                                     const float4* __restrict__ sp2,
                                                     const float4* __restrict__ swq,
                                                     const float* __restrict__ flow,
                                                     const int* __restrict__ ksm_p,
                                                     float* __restrict__ curv2,
                                                     float* __restrict__ mcurv,
                                                     float* __restrict__ crossk,
                                                     float* __restrict__ accs) {
    const int tid = threadIdx.x, lane = tid & 63, wv = tid >> 6;
    const int b = blockIdx.x;

    if (b >= R3_END) {
        // ---- reverse chamfer: sp2-sorted queries vs swq-sorted window ----
        __shared__ float pmn[WPB];
        const int q0 = (b - R3_END) * (QPW_REV * WPB) + wv * QPW_REV;
        float nqx[QPW_REV], nqy[QPW_REV], nqz[QPW_REV], qx[QPW_REV], qs[QPW_REV], mn[QPW_REV];
#pragma unroll
        for (int qi = 0; qi < QPW_REV; ++qi) {
            float4 t = sp2[q0 + qi];
            qx[qi] = t.x;
            nqx[qi] = -2.f * t.x; nqy[qi] = -2.f * t.y; nqz[qi] = -2.f * t.z;
            qs[qi] = fmaf(t.z, t.z, fmaf(t.y, t.y, t.x * t.x));
            mn[qi] = BIGF;
        }
        const int center = wave_bsearch(swq, qx[QPW_REV / 2]);
        const int lo = min(max(center - WREV / 2, 0), N_PTS - WREV);
        const float4* cp = swq + lo + lane;
        for (int it = 0; it < NIT_REV; ++it) {
            float4 p0 = cp[it * 128 + 0];
            float4 p1 = cp[it * 128 + 64];
            float s0 = fmaf(p0.z, p0.z, fmaf(p0.y, p0.y, p0.x * p0.x));
            float s1 = fmaf(p1.z, p1.z, fmaf(p1.y, p1.y, p1.x * p1.x));
#pragma unroll
            for (int qi = 0; qi < QPW_REV; ++qi) {
                float d0 = fmaf(p0.x, nqx[qi], fmaf(p0.y, nqy[qi], fmaf(p0.z, nqz[qi], s0)));
                float d1 = fmaf(p1.x, nqx[qi], fmaf(p1.y, nqy[qi], fmaf(p1.z, nqz[qi], s1)));
                mn[qi] = fminf(mn[qi], fminf(d0, d1));
            }
        }
        const bool okl = (lo == 0), okr = (lo + WREV >= N_PTS);
        const float xl = okl ? 0.f : swq[lo - 1].x;
        const float xr = okr ? 0.f : swq[lo + WREV].x;
        float s = 0.f;
#pragma unroll
        for (int qi = 0; qi < QPW_REV; ++qi) {
            float v = mn[qi];
#pragma unroll
            for (int off = 1; off < 64; off <<= 1) v = fminf(v, __shfl_xor(v, off));
            float Gm = cert_bound(okl, okr, xl, xr, qx[qi], qs[qi]);
            if (!(Gm > v)) {
                // exact full min over original wq (rare)
                float mm = BIGF;
                const float4* fp = wq + lane;
                for (int it2 = 0; it2 < N_PTS / 64; ++it2) {
                    float4 p = fp[it2 * 64];
                    float d = fmaf(p.x, nqx[qi], fmaf(p.y, nqy[qi], fmaf(p.z, nqz[qi], p.w)));
                    mm = fminf(mm, d);
                }
#pragma unroll
                for (int off = 1; off < 64; off <<= 1) mm = fminf(mm, __shfl_xor(mm, off));
                v = mm;
            }
            s += v + qs[qi];  // unshift
        }
        if (lane == 0) pmn[wv] = s;
        __syncthreads();
        if (tid == 0) atomicAdd(&accs[1], pmn[0] + pmn[1] + pmn[2] + pmn[3]);
        return;
    }

    const int role = (b < R0_END) ? 0 : (b < R1_END) ? 1 : 3;
    const int blk = b - ((role == 0) ? 0 : (role == 1) ? R0_END : R1_END);
    const int q0 = blk * QPB + wv * QPW;

    const float4* qS = (role == 0) ? sp2 : (role == 1) ? sp1 : swq;
    const float4* cS = (role == 1) ? sp1 : sp2;
    const float4* cOrig = (role == 1) ? p1q : p2q;
    float nqx[QPW], nqy[QPW], nqz[QPW], qx[QPW], qs[QPW];
    int qo[QPW];
#pragma unroll
    for (int qi = 0; qi < QPW; ++qi) {
        float4 t = qS[q0 + qi];
        qx[qi] = t.x;
        nqx[qi] = -2.f * t.x; nqy[qi] = -2.f * t.y; nqz[qi] = -2.f * t.z;
        qs[qi] = fmaf(t.z, t.z, fmaf(t.y, t.y, t.x * t.x));
        qo[qi] = (int)__float_as_uint(t.w);
    }
    const int center = (role == 3) ? wave_bsearch(cS, qx[QPW / 2]) : (q0 + QPW / 2);
    const int lo = min(max(center - WTOP / 2, 0), N_PTS - WTOP);
    float m1[QPW], m2[QPW], m3[QPW];
    scankw<QPW>(cS + lo, nqx, nqy, nqz, m1, m2, m3, lane);
    const bool okl = (lo == 0), okr = (lo + WTOP >= N_PTS);
    const float xl = okl ? 0.f : cS[lo - 1].x;
    const float xr = okr ? 0.f : cS[lo + WTOP].x;

    if (role == 3) {
        // ---- cross: K=5, store set keys (unordered) via mbcnt scatter ----
        constexpr int K = 5;
#pragma unroll
        for (int qi = 0; qi < QPW; ++qi) {
            float Gm = cert_bound(okl, okr, xl, xr, qx[qi], qs[qi]);
            float k1 = m1[qi], k2 = m2[qi], k3 = m3[qi]; bool q1, q2, q3; float km;
            select_set<K>(cOrig, nqx[qi], nqy[qi], nqz[qi], Gm, k1, k2, k3, q1, q2, q3, km, lane);
            const int q = qo[qi];
            unsigned long long b1 = __ballot(q1), b2 = __ballot(q2), b3 = __ballot(q3);
            int c1 = __popcll(b1), c2 = __popcll(b2);
            if (q1) crossk[prefcnt(b1) * N_PTS + q] = k1;
            if (q2) crossk[(c1 + prefcnt(b2)) * N_PTS + q] = k2;
            if (q3) crossk[(c1 + c2 + prefcnt(b3)) * N_PTS + q] = k3;
        }
        return;
    }

    constexpr int K = 10;
    if (role == 0) {
        // ---- curvature of pc2: set-sum of neighbor positions ----
#pragma unroll
        for (int qi = 0; qi < QPW; ++qi) {
            float Gm = cert_bound(okl, okr, xl, xr, qx[qi], qs[qi]);
            float k1 = m1[qi], k2 = m2[qi], k3 = m3[qi]; bool q1, q2, q3; float km;
            select_set<K>(cOrig, nqx[qi], nqy[qi], nqz[qi], Gm, k1, k2, k3, q1, q2, q3, km, lane);
            float ax = 0.f, ay = 0.f, az = 0.f;
            if (q1) { float4 nb = p2q[keyidx(k1)]; ax += nb.x; ay += nb.y; az += nb.z; }
            if (q2) { float4 nb = p2q[keyidx(k2)]; ax += nb.x; ay += nb.y; az += nb.z; }
            if (q3) { float4 nb = p2q[keyidx(k3)]; ax += nb.x; ay += nb.y; az += nb.z; }
            wave_add3(ax, ay, az);
            if (lane == 0) {
                // R26 FIX: original exact form (R25 wrote ax-5*nq = ax+10*t — sign bug)
                const int q = qo[qi];
                float4 t = p2q[q];
                curv2[q * 3 + 0] = (ax - 10.f * t.x) * (1.f / 9.f);
                curv2[q * 3 + 1] = (ay - 10.f * t.y) * (1.f / 9.f);
                curv2[q * 3 + 2] = (az - 10.f * t.z) * (1.f / 9.f);
            }
        }
    } else {
        // ---- pc1 self-kNN set -> moved_curv + smoothness (exclude max member) ----
        __shared__ float psm[WPB];
        const bool iall = (ksm_p[0] >= 10);   // ksm = 9 in practice: exclude km
        float smsum = 0.f;
#pragma unroll
        for (int qi = 0; qi < QPW; ++qi) {
            float Gm = cert_bound(okl, okr, xl, xr, qx[qi], qs[qi]);
            float k1 = m1[qi], k2 = m2[qi], k3 = m3[qi]; bool q1, q2, q3; float km;
            select_set<K>(cOrig, nqx[qi], nqy[qi], nqz[qi], Gm, k1, k2, k3, q1, q2, q3, km, lane);
            const int q = qo[qi];
            const float fqx = flow[q * 3 + 0], fqy = flow[q * 3 + 1], fqz = flow[q * 3 + 2];
            float ax = 0.f, ay = 0.f, az = 0.f, sm = 0.f;
            if (q1) {
                const int ni = keyidx(k1);
                float4 nb = wq[ni];
                ax += nb.x; ay += nb.y; az += nb.z;
                if (iall || k1 < km) {
                    float dx = flow[ni * 3 + 0] - fqx, dy = flow[ni * 3 + 1] - fqy, dz = flow[ni * 3 + 2] - fqz;
                    float sq = dx * dx + dy * dy + dz * dz;
                    sm += (sq == 0.f) ? 0.f : sqrtf(sq);
                }
            }
            if (q2) {
                const int ni = keyidx(k2);
                float4 nb = wq[ni];
                ax += nb.x; ay += nb.y; az += nb.z;
                if (iall || k2 < km) {
                    float dx = flow[ni * 3 + 0] - fqx, dy = flow[ni * 3 + 1] - fqy, dz = flow[ni * 3 + 2] - fqz;
                    float sq = dx * dx + dy * dy + dz * dz;
                    sm += (sq == 0.f) ? 0.f : sqrtf(sq);
                }
            }
            if (q3) {
                const int ni = keyidx(k3);
                float4 nb = wq[ni];
                ax += nb.x; ay += nb.y; az += nb.z;
                if (iall || k3 < km) {
                    float dx = flow[ni * 3 + 0] - fqx, dy = flow[ni * 3 + 1] - fqy, dz = flow[ni * 3 + 2] - fqz;
                    float sq = dx * dx + dy * dy + dz * dz;
                    sm += (sq == 0.f) ? 0.f : sqrtf(sq);
                }
            }
            wave_add4(ax, ay, az, sm);
            smsum += sm * 0.125f;  // /8.0 hard-coded in reference
            if (lane == 0) {
                float4 wqp = wq[q];
                mcurv[q * 3 + 0] = (ax - 10.f * wqp.x) * (1.f / 9.f);
                mcurv[q * 3 + 1] = (ay - 10.f * wqp.y) * (1.f / 9.f);
                mcurv[q * 3 + 2] = (az - 10.f * wqp.z) * (1.f / 9.f);
            }
        }
        if (lane == 0) psm[wv] = smsum;
        __syncthreads();
        if (tid == 0) atomicAdd(&accs[2], psm[0] + psm[1] + psm[2] + psm[3]);
    }
}

// ---- epilogue: exact-dist IDW + chamfer1/curv sums; last block finalizes ----
__global__ __launch_bounds__(64) void epi_kernel(const float* __restrict__ crossk,
                                                 const float4* __restrict__ wq,
                                                 const float4* __restrict__ p2q,
                                                 const float* __restrict__ curv2,
                                                 const float* __restrict__ mcurv,
                                                 float* __restrict__ accs,
                                                 int* __restrict__ done,
                                                 float* __restrict__ out) {
    const int lane = threadIdx.x & 63;
    const int q = blockIdx.x * 64 + threadIdx.x;
    constexpr int K = 5;
    float4 qp = wq[q];
    float bd[K]; int bi[K];
#pragma unroll
    for (int r = 0; r < K; ++r) {
        bi[r] = keyidx(crossk[r * N_PTS + q]);
        float4 nb = p2q[bi[r]];
        float dx = qp.x - nb.x, dy = qp.y - nb.y, dz = qp.z - nb.z;
        bd[r] = dx * dx + dy * dy + dz * dz;   // exact squared distance
    }
    float w[K], wsum = 0.f;
#pragma unroll
    for (int r = 0; r < K; ++r) { w[r] = 1.f / (bd[r] + 1e-8f); wsum += w[r]; }
    float ix = 0.f, iy = 0.f, iz = 0.f;
#pragma unroll
    for (int r = 0; r < K; ++r) {
        float ww = w[r] / wsum;
        ix += ww * curv2[bi[r] * 3 + 0];
        iy += ww * curv2[bi[r] * 3 + 1];
        iz += ww * curv2[bi[r] * 3 + 2];
    }
    float dx = ix - mcurv[q * 3 + 0];
    float dy = iy - mcurv[q * 3 + 1];
    float dz = iz - mcurv[q * 3 + 2];
    float d1 = fminf(fminf(fminf(bd[0], bd[1]), fminf(bd[2], bd[3])), bd[4]);  // unordered set
    float cv = dx * dx + dy * dy + dz * dz;
#pragma unroll
    for (int off = 1; off < 64; off <<= 1) {
        d1 += __shfl_xor(d1, off);
        cv += __shfl_xor(cv, off);
    }
    if (lane == 0) {
        atomicAdd(&accs[0], d1);
        atomicAdd(&accs[3], cv);
        __threadfence();
        int v = atomicAdd(done, 1);
        if (v == (int)gridDim.x - 1) {
            out[0] = W_CHAM * (accs[0] + accs[1]) + W_CURV * accs[3] + W_SMOO * accs[2];
        }
    }
}

extern "C" void kernel_launch(void* const* d_in, const int* in_sizes, int n_in,
                              void* d_out, int out_size, void* d_ws, size_t ws_size,
                              hipStream_t stream) {
    const float* flow   = (const float*)d_in[0];  // registration_pred (1,N,3)
    const float* gt     = (const float*)d_in[1];  // registration_gt   (1,N,3)
    const float* coords = (const float*)d_in[2];  // (N,3)
    const int*   ksm    = (const int*)d_in[3];    // smoothness_k (=9)

    float4* p1q   = (float4*)d_ws;           // N float4 (xyz,|p|^2)
    float4* p2q   = p1q + N_PTS;
    float4* wq    = p2q + N_PTS;
    float4* sp1   = wq + N_PTS;              // sorted-by-x (xyz, idx bits)
    float4* sp2   = sp1 + N_PTS;
    float4* swq   = sp2 + N_PTS;
    float*  curv2 = (float*)(swq + N_PTS);   // 3N
    float*  mcurv = curv2 + 3 * N_PTS;       // 3N
    float*  crossk = mcurv + 3 * N_PTS;      // 5N keys
    float*  accs  = crossk + 5 * N_PTS;      // 8
    int*    done  = (int*)(accs + 8);        // 1
    float*  out   = (float*)d_out;

    prep_kernel<<<(N_PTS + 255) / 256, 256, 0, stream>>>(flow, gt, coords, p1q, p2q, wq,
                                                         accs, done);
    sort_kernel<<<3, 1024, 0, stream>>>(p1q, p2q, wq, sp1, sp2, swq);
    fused4_kernel<<<GRID_TOTAL, 256, 0, stream>>>(p1q, p2q, wq, sp1, sp2, swq, flow, ksm,
                                                  curv2, mcurv, crossk, accs);
    epi_kernel<<<N_PTS / 64, 64, 0, stream>>>(crossk, wq, p2q, curv2, mcurv,
                                              accs, done, out);
}

// Round 10
// 143.908 us; speedup vs baseline: 1.3809x; 1.3809x over previous
//
#include <hip/hip_runtime.h>
#include <math.h>

#define N_PTS 8192
#define QPW 4                 // queries per wave (top-K roles)
#define QPW_REV 8             // queries per wave (reverse chamfer role)
#define WPB 4                 // waves per block
#define QPB (QPW * WPB)       // 16 queries per block (top-K roles)
#define BLKS_TOPK (N_PTS / QPB)        // 512 blocks per top-K role
#define BLKS_REV  (N_PTS / (QPW_REV * WPB))  // 256 blocks for rev

#define R0_END BLKS_TOPK                  // 512   curv2 scan
#define R1_END (2 * BLKS_TOPK)            // 1024  pc1 scan
#define R3_END (3 * BLKS_TOPK)            // 1536  cross scan
#define GRID_TOTAL (3 * BLKS_TOPK + BLKS_REV)  // 1792

// R27: LDS candidate staging (shared by the block's 4 waves)
#define STRIP 512                       // candidates per strip (8 KB float4)
#define NSTRIP (N_PTS / STRIP)          // 16 strips

// F_CHAMFER*ALPHA0 = 0.02, F_CURVATURE*ALPHA0 = 0.006, F_SMOOTH*ALPHA0 = 0.01
#define W_CHAM 0.02f
#define W_CURV 0.006f
#define W_SMOO 0.01f

#define BIGF 1e30f
#define IDX_MASK 0x1FFFu
#define KEY_MASK 0xFFFFE000u

__device__ __forceinline__ float mkkey(float d, unsigned idx) {
    return __uint_as_float((__float_as_uint(d) & KEY_MASK) | idx);
}
__device__ __forceinline__ int keyidx(float k) {
    return (int)(__float_as_uint(k) & IDX_MASK);
}
// monotonic float-bits -> unsigned map (order-preserving)
__device__ __forceinline__ unsigned monou(float k) {
    int b = __float_as_int(k);
    return (unsigned)(b ^ ((b >> 31) | 0x80000000));
}
// prefix popcount of mask below this lane
__device__ __forceinline__ int prefcnt(unsigned long long m) {
    return __builtin_amdgcn_mbcnt_hi((unsigned)(m >> 32),
           __builtin_amdgcn_mbcnt_lo((unsigned)m, 0));
}

// ---- value-only sorted insert (fallback path only; proven) ----
template <int K>
__device__ __forceinline__ void kinsert(float kv, float (&bd)[K]) {
    bd[K - 1] = kv;
#pragma unroll
    for (int s = K - 1; s > 0; --s) {
        float lo = fminf(bd[s - 1], bd[s]);
        float hi = fmaxf(bd[s - 1], bd[s]);
        bd[s - 1] = lo; bd[s] = hi;
    }
}

// ---- proven sorted merge (cold failsafe only) ----
template <int K>
__device__ void merge_keys(float m1, float m2, float m3, float (&bd)[K], int lane) {
    float h0 = m1, h1 = m2, h2 = m3;
#pragma unroll
    for (int r = 0; r < K; ++r) {
        float bv = h0;
#pragma unroll
        for (int off = 1; off < 64; off <<= 1) bv = fminf(bv, __shfl_xor(bv, off));
        bd[r] = bv;
        if (h0 == bv) { h0 = h1; h1 = h2; h2 = BIGF; }
    }
}

// ---- exact fixed-tau FULL rescan in key space (proven; reads global) ----
template <int K>
__device__ void tau_rescan(const float4* __restrict__ cand,
                           float nqx, float nqy, float nqz, float tau,
                           float (&bd)[K], int lane) {
#pragma unroll
    for (int r = 0; r < K; ++r) bd[r] = BIGF;
    const float4* cp = cand + lane;
    unsigned ib = (unsigned)lane;
    for (int it = 0; it < N_PTS / 64; ++it) {
        float4 p = cp[it * 64];
        float d = fmaf(p.x, nqx, fmaf(p.y, nqy, fmaf(p.z, nqz, p.w)));
        float kc = mkkey(d, ib);
        unsigned long long m = __ballot(kc <= tau);
        while (m) {
            int b = __builtin_ctzll(m);
            m &= m - 1;
            float kv = __shfl(kc, b);
            if (kv < bd[K - 1]) kinsert<K>(kv, bd);
        }
        ib += 64;
    }
}

// ---- rank-pivot set selection: top-K as SET + km = max member (proven) ----
// Seeded binary search: range [wave_min(m1), wave_max(m1)] (exactness R18).
template <int K>
__device__ void select_set(const float4* __restrict__ cand,
                           float nqx, float nqy, float nqz,
                           float& k1, float& k2, float& k3,
                           bool& q1, bool& q2, bool& q3, float& km, int lane) {
    const unsigned u1 = monou(k1), u2 = monou(k2), u3 = monou(k3);
    float bmn = k1, bmx = k1;
#pragma unroll
    for (int off = 1; off < 64; off <<= 1) {
        bmn = fminf(bmn, __shfl_xor(bmn, off));
        bmx = fmaxf(bmx, __shfl_xor(bmx, off));
    }
    unsigned lo = monou(bmn), hi = monou(bmx), piv = 0u;
    int cnt = -1;
    unsigned long long b3 = 0ull;
    for (int it = 0; it < 34; ++it) {
        piv = lo + ((hi - lo) >> 1);
        unsigned long long b1 = __ballot(u1 <= piv);
        unsigned long long b2 = __ballot(u2 <= piv);
        b3 = __ballot(u3 <= piv);
        cnt = __popcll(b1) + __popcll(b2) + __popcll(b3);
        if (cnt == K) break;
        if (cnt < K) lo = piv + 1; else hi = piv - 1;
    }
    bool setok = (cnt == K);
    bool fail;
    float bdK[K];
    if (setok) {
        q1 = (u1 <= piv); q2 = (u2 <= piv); q3 = (u3 <= piv);
        float t = q3 ? k3 : (q2 ? k2 : (q1 ? k1 : -BIGF));
#pragma unroll
        for (int off = 1; off < 64; off <<= 1) t = fmaxf(t, __shfl_xor(t, off));
        km = t;
        fail = (b3 != 0ull);   // some lane contributed its 3rd -> 4th may be hidden
    } else {
        merge_keys<K>(k1, k2, k3, bdK, lane);   // mathematically unreachable failsafe
        km = bdK[K - 1];
        fail = (__ballot(k3 <= km) != 0ull);
    }
    if (fail) { tau_rescan<K>(cand, nqx, nqy, nqz, km, bdK, lane); setok = false; }
    if (!setok) {
        float kv = BIGF;
#pragma unroll
        for (int r = 0; r < K; ++r) if (lane == r) kv = bdK[r];
        k1 = kv; k2 = BIGF; k3 = BIGF;
        q1 = (lane < K); q2 = false; q3 = false;
        km = bdK[K - 1];
    }
}

__device__ __forceinline__ void wave_add3(float& a, float& b, float& c) {
#pragma unroll
    for (int off = 1; off < 64; off <<= 1) {
        a += __shfl_xor(a, off);
        b += __shfl_xor(b, off);
        c += __shfl_xor(c, off);
    }
}
__device__ __forceinline__ void wave_add4(float& a, float& b, float& c, float& d) {
#pragma unroll
    for (int off = 1; off < 64; off <<= 1) {
        a += __shfl_xor(a, off);
        b += __shfl_xor(b, off);
        c += __shfl_xor(c, off);
        d += __shfl_xor(d, off);
    }
}

// ---- R27: LDS-staged branchless Q-query key scan ----
// Block-cooperative: strip s+1 is loaded into the other LDS buffer while
// strip s is processed; ONE __syncthreads per strip. Candidate order and
// ib index packing identical to the proven global-stream scank.
template <int Q>
__device__ __forceinline__ void scank_lds(const float4* __restrict__ cand,
                                          float4 (&tile)[2][STRIP],
                                          const float (&nqx)[Q], const float (&nqy)[Q],
                                          const float (&nqz)[Q],
                                          float (&m1)[Q], float (&m2)[Q], float (&m3)[Q],
                                          int tid, int lane) {
#pragma unroll
    for (int qi = 0; qi < Q; ++qi) { m1[qi] = BIGF; m2[qi] = BIGF; m3[qi] = BIGF; }
    // prologue: strip 0
    tile[0][tid] = cand[tid];
    tile[0][tid + 256] = cand[tid + 256];
    __syncthreads();
    for (int s = 0; s < NSTRIP; ++s) {
        const int cur = s & 1, nb = cur ^ 1;
        if (s + 1 < NSTRIP) {
            tile[nb][tid] = cand[(s + 1) * STRIP + tid];
            tile[nb][tid + 256] = cand[(s + 1) * STRIP + tid + 256];
        }
        const float4* tp = tile[cur];
        unsigned ib = (unsigned)(s * STRIP + lane);
#pragma unroll
        for (int j = 0; j < STRIP / 256; ++j) {
            float4 p0 = tp[j * 256 + lane];
            float4 p1 = tp[j * 256 + 64 + lane];
            float4 p2 = tp[j * 256 + 128 + lane];
            float4 p3 = tp[j * 256 + 192 + lane];
#pragma unroll
            for (int qi = 0; qi < Q; ++qi) {
                float d0 = fmaf(p0.x, nqx[qi], fmaf(p0.y, nqy[qi], fmaf(p0.z, nqz[qi], p0.w)));
                float k0 = mkkey(d0, ib);
                m3[qi] = __builtin_amdgcn_fmed3f(k0, m2[qi], m3[qi]);
                m2[qi] = __builtin_amdgcn_fmed3f(k0, m1[qi], m2[qi]);
                m1[qi] = fminf(k0, m1[qi]);
                float d1 = fmaf(p1.x, nqx[qi], fmaf(p1.y, nqy[qi], fmaf(p1.z, nqz[qi], p1.w)));
                float k1 = mkkey(d1, ib + 64u);
                m3[qi] = __builtin_amdgcn_fmed3f(k1, m2[qi], m3[qi]);
                m2[qi] = __builtin_amdgcn_fmed3f(k1, m1[qi], m2[qi]);
                m1[qi] = fminf(k1, m1[qi]);
                float d2 = fmaf(p2.x, nqx[qi], fmaf(p2.y, nqy[qi], fmaf(p2.z, nqz[qi], p2.w)));
                float k2 = mkkey(d2, ib + 128u);
                m3[qi] = __builtin_amdgcn_fmed3f(k2, m2[qi], m3[qi]);
                m2[qi] = __builtin_amdgcn_fmed3f(k2, m1[qi], m2[qi]);
                m1[qi] = fminf(k2, m1[qi]);
                float d3 = fmaf(p3.x, nqx[qi], fmaf(p3.y, nqy[qi], fmaf(p3.z, nqz[qi], p3.w)));
                float k3 = mkkey(d3, ib + 192u);
                m3[qi] = __builtin_amdgcn_fmed3f(k3, m2[qi], m3[qi]);
                m2[qi] = __builtin_amdgcn_fmed3f(k3, m1[qi], m2[qi]);
                m1[qi] = fminf(k3, m1[qi]);
            }
            ib += 256u;
        }
        __syncthreads();
    }
}

// ---- kernel 0: pack point sets as float4 (xyz,|p|^2), zero accumulators ----
__global__ void prep_kernel(const float* __restrict__ flow, const float* __restrict__ gt,
                            const float* __restrict__ coords,
                            float4* __restrict__ p1q, float4* __restrict__ p2q,
                            float4* __restrict__ wq, float* __restrict__ accs,
                            int* __restrict__ done) {
    int i = blockIdx.x * blockDim.x + threadIdx.x;
    if (i < N_PTS) {
        float cx = coords[3 * i + 0], cy = coords[3 * i + 1], cz = coords[3 * i + 2];
        float p2x = cx + gt[3 * i + 0], p2y = cy + gt[3 * i + 1], p2z = cz + gt[3 * i + 2];
        float wx = cx + flow[3 * i + 0], wy = cy + flow[3 * i + 1], wz = cz + flow[3 * i + 2];
        p1q[i] = make_float4(cx, cy, cz, cx * cx + cy * cy + cz * cz);
        p2q[i] = make_float4(p2x, p2y, p2z, p2x * p2x + p2y * p2y + p2z * p2z);
        wq[i]  = make_float4(wx, wy, wz, wx * wx + wy * wy + wz * wz);
    }
    if (i < 8) accs[i] = 0.0f;
    if (i == 8) done[0] = 0;
}

// ---- fused kernel: duration-balanced roles + LDS candidate staging ----
// Plain __launch_bounds__(256): NEVER the 2-arg form (R18/R22 spill disasters).
__global__ __launch_bounds__(256) void fused4_kernel(const float4* __restrict__ p1q,
                                                     const float4* __restrict__ p2q,
                                                     const float4* __restrict__ wq,
                                                     const float* __restrict__ flow,
                                                     const int* __restrict__ ksm_p,
                                                     float* __restrict__ curv2,
                                                     float* __restrict__ mcurv,
                                                     float* __restrict__ crossk,
                                                     float* __restrict__ accs) {
    const int tid = threadIdx.x, lane = tid & 63, wv = tid >> 6;
    const int b = blockIdx.x;
    __shared__ float4 tile[2][STRIP];   // 16 KB; 7 blocks/CU x 16KB = 112KB < 160KB

    if (b >= R3_END) {
        // ---- reverse chamfer, QPW_REV queries per wave, LDS-staged ----
        __shared__ float pmn[WPB];
        const int q0 = (b - R3_END) * (QPW_REV * WPB) + wv * QPW_REV;
        float nqx[QPW_REV], nqy[QPW_REV], nqz[QPW_REV], qw[QPW_REV], mn[QPW_REV];
#pragma unroll
        for (int qi = 0; qi < QPW_REV; ++qi) {
            float4 t = p2q[q0 + qi];
            nqx[qi] = -2.f * t.x; nqy[qi] = -2.f * t.y; nqz[qi] = -2.f * t.z;
            qw[qi] = t.w; mn[qi] = BIGF;
        }
        tile[0][tid] = wq[tid];
        tile[0][tid + 256] = wq[tid + 256];
        __syncthreads();
        for (int s = 0; s < NSTRIP; ++s) {
            const int cur = s & 1, nb = cur ^ 1;
            if (s + 1 < NSTRIP) {
                tile[nb][tid] = wq[(s + 1) * STRIP + tid];
                tile[nb][tid + 256] = wq[(s + 1) * STRIP + tid + 256];
            }
            const float4* tp = tile[cur];
#pragma unroll
            for (int j = 0; j < STRIP / 128; ++j) {
                float4 p0 = tp[j * 128 + lane];
                float4 p1 = tp[j * 128 + 64 + lane];
#pragma unroll
                for (int qi = 0; qi < QPW_REV; ++qi) {
                    float d0 = fmaf(p0.x, nqx[qi], fmaf(p0.y, nqy[qi], fmaf(p0.z, nqz[qi], p0.w)));
                    float d1 = fmaf(p1.x, nqx[qi], fmaf(p1.y, nqy[qi], fmaf(p1.z, nqz[qi], p1.w)));
                    mn[qi] = fminf(mn[qi], fminf(d0, d1));
                }
            }
            __syncthreads();
        }
        float s = 0.f;
#pragma unroll
        for (int qi = 0; qi < QPW_REV; ++qi) {
            float v = mn[qi];
#pragma unroll
            for (int off = 1; off < 64; off <<= 1) v = fminf(v, __shfl_xor(v, off));
            s += v + qw[qi];  // unshift
        }
        if (lane == 0) pmn[wv] = s;
        __syncthreads();
        if (tid == 0) atomicAdd(&accs[1], pmn[0] + pmn[1] + pmn[2] + pmn[3]);
        return;
    }

    const int role = (b < R0_END) ? 0 : (b < R1_END) ? 1 : 3;
    const int blk = b - ((role == 0) ? 0 : (role == 1) ? R0_END : R1_END);
    const int q0 = blk * QPB + wv * QPW;

    const float4* qsrc = (role == 0) ? p2q : (role == 1) ? p1q : wq;
    const float4* cand = (role == 1) ? p1q : p2q;
    float nqx[QPW], nqy[QPW], nqz[QPW];
#pragma unroll
    for (int qi = 0; qi < QPW; ++qi) {
        float4 t = qsrc[q0 + qi];
        nqx[qi] = -2.f * t.x; nqy[qi] = -2.f * t.y; nqz[qi] = -2.f * t.z;
    }
    float m1[QPW], m2[QPW], m3[QPW];
    scank_lds<QPW>(cand, tile, nqx, nqy, nqz, m1, m2, m3, tid, lane);

    if (role == 3) {
        // ---- cross: K=5, store set keys (unordered) via mbcnt scatter ----
        constexpr int K = 5;
#pragma unroll
        for (int qi = 0; qi < QPW; ++qi) {
            float k1 = m1[qi], k2 = m2[qi], k3 = m3[qi]; bool q1, q2, q3; float km;
            select_set<K>(p2q, nqx[qi], nqy[qi], nqz[qi], k1, k2, k3, q1, q2, q3, km, lane);
            const int q = q0 + qi;
            unsigned long long b1 = __ballot(q1), b2 = __ballot(q2), b3 = __ballot(q3);
            int c1 = __popcll(b1), c2 = __popcll(b2);
            if (q1) crossk[prefcnt(b1) * N_PTS + q] = k1;
            if (q2) crossk[(c1 + prefcnt(b2)) * N_PTS + q] = k2;
            if (q3) crossk[(c1 + c2 + prefcnt(b3)) * N_PTS + q] = k3;
        }
        return;
    }

    constexpr int K = 10;
    if (role == 0) {
        // ---- curvature of pc2: set-sum of neighbor positions ----
#pragma unroll
        for (int qi = 0; qi < QPW; ++qi) {
            float k1 = m1[qi], k2 = m2[qi], k3 = m3[qi]; bool q1, q2, q3; float km;
            select_set<K>(p2q, nqx[qi], nqy[qi], nqz[qi], k1, k2, k3, q1, q2, q3, km, lane);
            float ax = 0.f, ay = 0.f, az = 0.f;
            if (q1) { float4 nb = p2q[keyidx(k1)]; ax += nb.x; ay += nb.y; az += nb.z; }
            if (q2) { float4 nb = p2q[keyidx(k2)]; ax += nb.x; ay += nb.y; az += nb.z; }
            if (q3) { float4 nb = p2q[keyidx(k3)]; ax += nb.x; ay += nb.y; az += nb.z; }
            wave_add3(ax, ay, az);
            if (lane == 0) {
                const int q = q0 + qi;
                float4 t = p2q[q];
                curv2[q * 3 + 0] = (ax - 10.f * t.x) * (1.f / 9.f);
                curv2[q * 3 + 1] = (ay - 10.f * t.y) * (1.f / 9.f);
                curv2[q * 3 + 2] = (az - 10.f * t.z) * (1.f / 9.f);
            }
        }
    } else {
        // ---- pc1 self-kNN set -> moved_curv + smoothness (exclude max member) ----
        __shared__ float psm[WPB];
        const bool iall = (ksm_p[0] >= 10);   // ksm = 9 in practice: exclude km
        float smsum = 0.f;
#pragma unroll
        for (int qi = 0; qi < QPW; ++qi) {
            float k1 = m1[qi], k2 = m2[qi], k3 = m3[qi]; bool q1, q2, q3; float km;
            select_set<K>(p1q, nqx[qi], nqy[qi], nqz[qi], k1, k2, k3, q1, q2, q3, km, lane);
            const int q = q0 + qi;
            const float fqx = flow[q * 3 + 0], fqy = flow[q * 3 + 1], fqz = flow[q * 3 + 2];
            float ax = 0.f, ay = 0.f, az = 0.f, sm = 0.f;
            if (q1) {
                const int ni = keyidx(k1);
                float4 nb = wq[ni];
                ax += nb.x; ay += nb.y; az += nb.z;
                if (iall || k1 < km) {
                    float dx = flow[ni * 3 + 0] - fqx, dy = flow[ni * 3 + 1] - fqy, dz = flow[ni * 3 + 2] - fqz;
                    float sq = dx * dx + dy * dy + dz * dz;
                    sm += (sq == 0.f) ? 0.f : sqrtf(sq);
                }
            }
            if (q2) {
                const int ni = keyidx(k2);
                float4 nb = wq[ni];
                ax += nb.x; ay += nb.y; az += nb.z;
                if (iall || k2 < km) {
                    float dx = flow[ni * 3 + 0] - fqx, dy = flow[ni * 3 + 1] - fqy, dz = flow[ni * 3 + 2] - fqz;
                    float sq = dx * dx + dy * dy + dz * dz;
                    sm += (sq == 0.f) ? 0.f : sqrtf(sq);
                }
            }
            if (q3) {
                const int ni = keyidx(k3);
                float4 nb = wq[ni];
                ax += nb.x; ay += nb.y; az += nb.z;
                if (iall || k3 < km) {
                    float dx = flow[ni * 3 + 0] - fqx, dy = flow[ni * 3 + 1] - fqy, dz = flow[ni * 3 + 2] - fqz;
                    float sq = dx * dx + dy * dy + dz * dz;
                    sm += (sq == 0.f) ? 0.f : sqrtf(sq);
                }
            }
            wave_add4(ax, ay, az, sm);
            smsum += sm * 0.125f;  // /8.0 hard-coded in reference
            if (lane == 0) {
                float4 wqp = wq[q];
                mcurv[q * 3 + 0] = (ax - 10.f * wqp.x) * (1.f / 9.f);
                mcurv[q * 3 + 1] = (ay - 10.f * wqp.y) * (1.f / 9.f);
                mcurv[q * 3 + 2] = (az - 10.f * wqp.z) * (1.f / 9.f);
            }
        }
        if (lane == 0) psm[wv] = smsum;
        __syncthreads();
        if (tid == 0) atomicAdd(&accs[2], psm[0] + psm[1] + psm[2] + psm[3]);
    }
}

// ---- epilogue: exact-dist IDW + chamfer1/curv sums; last block finalizes ----
__global__ __launch_bounds__(64) void epi_kernel(const float* __restrict__ crossk,
                                                 const float4* __restrict__ wq,
                                                 const float4* __restrict__ p2q,
                                                 const float* __restrict__ curv2,
                                                 const float* __restrict__ mcurv,
                                                 float* __restrict__ accs,
                                                 int* __restrict__ done,
                                                 float* __restrict__ out) {
    const int lane = threadIdx.x & 63;
    const int q = blockIdx.x * 64 + threadIdx.x;
    constexpr int K = 5;
    float4 qp = wq[q];
    float bd[K]; int bi[K];
#pragma unroll
    for (int r = 0; r < K; ++r) {
        bi[r] = keyidx(crossk[r * N_PTS + q]);
        float4 nb = p2q[bi[r]];
        float dx = qp.x - nb.x, dy = qp.y - nb.y, dz = qp.z - nb.z;
        bd[r] = dx * dx + dy * dy + dz * dz;   // exact squared distance
    }
    float w[K], wsum = 0.f;
#pragma unroll
    for (int r = 0; r < K; ++r) { w[r] = 1.f / (bd[r] + 1e-8f); wsum += w[r]; }
    float ix = 0.f, iy = 0.f, iz = 0.f;
#pragma unroll
    for (int r = 0; r < K; ++r) {
        float ww = w[r] / wsum;
        ix += ww * curv2[bi[r] * 3 + 0];
        iy += ww * curv2[bi[r] * 3 + 1];
        iz += ww * curv2[bi[r] * 3 + 2];
    }
    float dx = ix - mcurv[q * 3 + 0];
    float dy = iy - mcurv[q * 3 + 1];
    float dz = iz - mcurv[q * 3 + 2];
    float d1 = fminf(fminf(fminf(bd[0], bd[1]), fminf(bd[2], bd[3])), bd[4]);  // unordered set
    float cv = dx * dx + dy * dy + dz * dz;
#pragma unroll
    for (int off = 1; off < 64; off <<= 1) {
        d1 += __shfl_xor(d1, off);
        cv += __shfl_xor(cv, off);
    }
    if (lane == 0) {
        atomicAdd(&accs[0], d1);
        atomicAdd(&accs[3], cv);
        __threadfence();
        int v = atomicAdd(done, 1);
        if (v == (int)gridDim.x - 1) {
            out[0] = W_CHAM * (accs[0] + accs[1]) + W_CURV * accs[3] + W_SMOO * accs[2];
        }
    }
}

extern "C" void kernel_launch(void* const* d_in, const int* in_sizes, int n_in,
                              void* d_out, int out_size, void* d_ws, size_t ws_size,
                              hipStream_t stream) {
    const float* flow   = (const float*)d_in[0];  // registration_pred (1,N,3)
    const float* gt     = (const float*)d_in[1];  // registration_gt   (1,N,3)
    const float* coords = (const float*)d_in[2];  // (N,3)
    const int*   ksm    = (const int*)d_in[3];    // smoothness_k (=9)

    float4* p1q   = (float4*)d_ws;           // N float4 (xyz,|p|^2)
    float4* p2q   = p1q + N_PTS;
    float4* wq    = p2q + N_PTS;
    float*  curv2 = (float*)(wq + N_PTS);    // 3N
    float*  mcurv = curv2 + 3 * N_PTS;       // 3N
    float*  crossk = mcurv + 3 * N_PTS;      // 5N keys
    float*  accs  = crossk + 5 * N_PTS;      // 8
    int*    done  = (int*)(accs + 8);        // 1
    float*  out   = (float*)d_out;

    prep_kernel<<<(N_PTS + 255) / 256, 256, 0, stream>>>(flow, gt, coords, p1q, p2q, wq,
                                                         accs, done);
    fused4_kernel<<<GRID_TOTAL, 256, 0, stream>>>(p1q, p2q, wq, flow, ksm,
                                                  curv2, mcurv, crossk, accs);
    epi_kernel<<<N_PTS / 64, 64, 0, stream>>>(crossk, wq, p2q, curv2, mcurv,
                                              accs, done, out);
}